// Round 10
// baseline (186.034 us; speedup 1.0000x reference)
//
#include <hip/hip_runtime.h>

// Problem constants: B=32, D=64, H=W=32 -> N=32768 rows; K=1024 codes
#define OUT_OFF_Q 0          // quantized (straight-through fwd) [B,D,H,W]
#define OUT_OFF_VQ 2097152   // scalar vq_loss
#define OUT_OFF_PPL 2097153  // scalar perplexity
#define OUT_OFF_ENC 2097154  // encoded one-hot [N, K]

typedef __attribute__((ext_vector_type(8))) short short8;   // 8 bf16 (4 VGPRs)
typedef __attribute__((ext_vector_type(4))) float f32x4;    // MFMA C/D

__device__ __forceinline__ unsigned short f2bf(float f) {   // RNE f32->bf16
    unsigned u = __builtin_bit_cast(unsigned, f);
    u += 0x7fffu + ((u >> 16) & 1u);
    return (unsigned short)(u >> 16);
}
__device__ __forceinline__ float bf2f(unsigned short h) {
    unsigned u = ((unsigned)h) << 16;
    return __builtin_bit_cast(float, u);
}

// ---------------------------------------------------------------------------
// prep: build packed bf16 hi/lo A-fragment stream + ee[k] + zero counts.
// Efrag layout: [kt(64)][j(4)][lane(64)] x 16B, so the main k-loop's 4
// fragment loads are each perfectly coalesced (64 lanes x 16B contiguous).
__global__ __launch_bounds__(64) void vq_prep(
    const float* __restrict__ E, unsigned short* __restrict__ Efrag,
    float* __restrict__ ee, int* __restrict__ counts)
{
    const int t = threadIdx.x;
    const int kt = blockIdx.x;
    const int code = kt * 16 + (t & 15);
    const int q = t >> 4;

    const float* ep0 = E + code * 64 + q * 8;        // d = q*8 .. q*8+7
    const float* ep1 = ep0 + 32;                     // d = 32+q*8 ..
    short8 ah0, ah1, al0, al1;
    float s = 0.f;
    #pragma unroll
    for (int j = 0; j < 8; ++j) {
        float v0 = ep0[j];
        unsigned short h0 = f2bf(v0);
        ah0[j] = (short)h0;
        al0[j] = (short)f2bf(v0 - bf2f(h0));
        s = fmaf(v0, v0, s);
        float v1 = ep1[j];
        unsigned short h1 = f2bf(v1);
        ah1[j] = (short)h1;
        al1[j] = (short)f2bf(v1 - bf2f(h1));
        s = fmaf(v1, v1, s);
    }
    short8* dst = (short8*)Efrag + (size_t)kt * 256;  // 4 frag-planes x 64 lanes
    dst[0 * 64 + t] = ah0;
    dst[1 * 64 + t] = ah1;
    dst[2 * 64 + t] = al0;
    dst[3 * 64 + t] = al1;

    // ||e||^2: reduce partial s across the 4 quads sharing this code
    s += __shfl_xor(s, 16);
    s += __shfl_xor(s, 32);
    if (t < 16) ee[code] = s;

    // zero counts (4096 threads total, need 1024)
    const int gid = blockIdx.x * 64 + t;
    if (gid < 1024) counts[gid] = 0;
}

// ---------------------------------------------------------------------------
// main (barrier-free): 512 blocks x 256 threads = 2048 waves; each WAVE owns
// 16 consecutive n and scans ALL 1024 codes itself. Zero __syncthreads, zero
// LDS: argmin finishes with quad shuffles inside the wave; encode row indices
// come from __shfl; loss partial goes to a per-wave slot. Each wave flows
// straight from its k-loop into its own q-store + one-hot write burst, so
// compute and the 136MB write stream overlap across waves with no phase
// barriers. (R9 lesson: regular write-back stores, NOT nontemporal.
// R7 lesson: no device-scope fence / last-block finalize in here.)
__global__ __launch_bounds__(256, 4) void vq_main(
    const float* __restrict__ X, const float* __restrict__ E,
    const unsigned short* __restrict__ Efrag, const float* __restrict__ ee,
    float* __restrict__ out, int* __restrict__ counts,
    float* __restrict__ lossPart)
{
    const int t = threadIdx.x;
    const int l = t & 63;
    const int w = t >> 6;
    const int col = l & 15;          // n within this wave's 16-row tile
    const int quad = l >> 4;
    const int n0 = blockIdx.x * 64 + w * 16;   // this wave's first n
    const int b = n0 >> 10;
    const int hwb = n0 & 1023;

    // --- B-fragments (x) for this wave's one n-tile, hi & lo ---
    // B[k_gemm=d][n]: n = col, d = ks*32 + quad*8 + j
    short8 bh[2], bl[2];
    const float* xn = X + (size_t)b * 65536 + hwb + col;
    #pragma unroll
    for (int ks = 0; ks < 2; ++ks) {
        short8 vh, vl;
        #pragma unroll
        for (int j = 0; j < 8; ++j) {
            float v = xn[(size_t)(ks * 32 + quad * 8 + j) * 1024];
            unsigned short hb = f2bf(v);
            vh[j] = (short)hb;
            vl[j] = (short)f2bf(v - bf2f(hb));
        }
        bh[ks] = vh;
        bl[ks] = vl;
    }

    // --- k-loop: all 64 tiles of 16 codes; fragment loads coalesced ---
    float best = 3.4e38f;
    int   bidx = 0;
    const short8* fr = (const short8*)Efrag;
    #pragma unroll 4
    for (int kt = 0; kt < 64; ++kt) {
        const int kb = kt * 16;
        const short8* fb = fr + (size_t)kt * 256;
        short8 ah0 = fb[0 * 64 + l];     // 64 lanes x 16B contiguous
        short8 ah1 = fb[1 * 64 + l];
        short8 al0 = fb[2 * 64 + l];
        short8 al1 = fb[3 * 64 + l];
        f32x4 eev = *((const f32x4*)(ee + kb + quad * 4));   // L1-hot (4KB)
        f32x4 c = {0.f, 0.f, 0.f, 0.f};
        c = __builtin_amdgcn_mfma_f32_16x16x32_bf16(ah0, bh[0], c, 0, 0, 0);
        c = __builtin_amdgcn_mfma_f32_16x16x32_bf16(ah1, bh[1], c, 0, 0, 0);
        c = __builtin_amdgcn_mfma_f32_16x16x32_bf16(al0, bh[0], c, 0, 0, 0);
        c = __builtin_amdgcn_mfma_f32_16x16x32_bf16(al1, bh[1], c, 0, 0, 0);
        c = __builtin_amdgcn_mfma_f32_16x16x32_bf16(ah0, bl[0], c, 0, 0, 0);
        c = __builtin_amdgcn_mfma_f32_16x16x32_bf16(ah1, bl[1], c, 0, 0, 0);
        // C/D: col = lane&15 (n), row = quad*4 + r (k within tile)
        #pragma unroll
        for (int r = 0; r < 4; ++r) {
            float val = fmaf(-2.f, c[r], eev[r]);
            int k = kb + quad * 4 + r;
            if (val < best) { best = val; bidx = k; }
        }
    }

    // --- quad reduce (lanes l, l^16, l^32, l^48 share col); k ranges are
    // disjoint per quad, tie-break to lowest k = first occurrence ---
    {
        float ov = __shfl_xor(best, 16); int oi = __shfl_xor(bidx, 16);
        if (ov < best || (ov == best && oi < bidx)) { best = ov; bidx = oi; }
        ov = __shfl_xor(best, 32); oi = __shfl_xor(bidx, 32);
        if (ov < best || (ov == best && oi < bidx)) { best = ov; bidx = oi; }
    }
    // every lane now holds the final index for n = n0 + col

    // --- counts histogram: one atomic per n (quad 0 lanes) ---
    if (quad == 0) atomicAdd(&counts[bidx], 1);

    // --- quantized store + loss: lane (col, quad) covers d in [16q,16q+16) ---
    {
        const int fi = bidx;
        const int d0 = quad << 4;
        const float* er = E + ((size_t)fi << 6) + d0;
        float4 g0 = *(const float4*)(er);
        float4 g1 = *(const float4*)(er + 4);
        float4 g2 = *(const float4*)(er + 8);
        float4 g3 = *(const float4*)(er + 12);
        float q[16] = {g0.x, g0.y, g0.z, g0.w, g1.x, g1.y, g1.z, g1.w,
                       g2.x, g2.y, g2.z, g2.w, g3.x, g3.y, g3.z, g3.w};
        float* op = out + OUT_OFF_Q + (size_t)b * 65536 + hwb + col;
        const float* xp = X + (size_t)b * 65536 + hwb + col;
        float lsum = 0.f;
        #pragma unroll
        for (int dd = 0; dd < 16; ++dd) {
            const int d = d0 + dd;
            op[(size_t)d * 1024] = q[dd];           // 4x64B segments / instr
            float diff = q[dd] - xp[(size_t)d * 1024];   // L1-hot re-read
            lsum = fmaf(diff, diff, lsum);
        }
        #pragma unroll
        for (int off = 32; off; off >>= 1) lsum += __shfl_down(lsum, off);
        if (l == 0) lossPart[blockIdx.x * 4 + w] = lsum;   // per-wave slot
    }

    // --- one-hot encode: this wave writes its own 16 rows, f32x4 stores ---
    {
        f32x4* enc = (f32x4*)(out + OUT_OFF_ENC);
        #pragma unroll 4
        for (int rr = 0; rr < 16; ++rr) {
            const int ridx = __shfl(bidx, rr);      // lane rr: quad0, col=rr
            f32x4* erow = enc + (size_t)(n0 + rr) * 256;
            #pragma unroll
            for (int c4 = 0; c4 < 4; ++c4) {
                const int kb4 = (c4 << 8) + (l << 2);
                f32x4 v = {0.f, 0.f, 0.f, 0.f};
                const int dlt = ridx - kb4;
                if (dlt == 0) v.x = 1.f;
                else if (dlt == 1) v.y = 1.f;
                else if (dlt == 2) v.z = 1.f;
                else if (dlt == 3) v.w = 1.f;
                erow[(c4 << 6) + l] = v;            // 1KB contiguous / instr
            }
        }
    }
}

// ---------------------------------------------------------------------------
__global__ __launch_bounds__(1024) void vq_finalize(
    const int* __restrict__ counts, const float* __restrict__ lossPart,
    float* __restrict__ out)
{
    __shared__ float redp[16];
    __shared__ float redl[16];
    const int t = threadIdx.x;
    const float p = (float)counts[t] * (1.0f / 32768.0f);
    float v = p * logf(p + 1e-10f);
    float ls = lossPart[t] + lossPart[t + 1024];   // 2048 per-wave partials
    #pragma unroll
    for (int off = 32; off; off >>= 1) {
        v += __shfl_down(v, off);
        ls += __shfl_down(ls, off);
    }
    if ((t & 63) == 0) { redp[t >> 6] = v; redl[t >> 6] = ls; }
    __syncthreads();
    if (t == 0) {
        float s = 0.f, sl = 0.f;
        #pragma unroll
        for (int i = 0; i < 16; ++i) { s += redp[i]; sl += redl[i]; }
        out[OUT_OFF_PPL] = expf(-s);
        out[OUT_OFF_VQ] = 1.25f * sl * (1.0f / 2097152.0f);
    }
}

extern "C" void kernel_launch(void* const* d_in, const int* in_sizes, int n_in,
                              void* d_out, int out_size, void* d_ws, size_t ws_size,
                              hipStream_t stream) {
    const float* X = (const float*)d_in[0];   // [32, 64, 32, 32] fp32
    const float* E = (const float*)d_in[1];   // [1024, 64] fp32
    float* out = (float*)d_out;

    // ws layout
    int* counts = (int*)d_ws;                                      // 4 KiB
    float* lossPart = (float*)((char*)d_ws + 4096);                // 8 KiB (2048)
    float* ee = (float*)((char*)d_ws + 16384);                     // 4 KiB
    unsigned short* Efrag = (unsigned short*)((char*)d_ws + 20480);// 256 KiB

    vq_prep<<<64, 64, 0, stream>>>(E, Efrag, ee, counts);
    vq_main<<<512, 256, 0, stream>>>(X, E, Efrag, ee, out, counts, lossPart);
    vq_finalize<<<1, 1024, 0, stream>>>(counts, lossPart, out);
}

// Round 11
// 172.826 us; speedup vs baseline: 1.0764x; 1.0764x over previous
//
#include <hip/hip_runtime.h>

// Problem constants: B=32, D=64, H=W=32 -> N=32768 rows; K=1024 codes
#define OUT_OFF_Q 0          // quantized (straight-through fwd) [B,D,H,W]
#define OUT_OFF_VQ 2097152   // scalar vq_loss
#define OUT_OFF_PPL 2097153  // scalar perplexity
#define OUT_OFF_ENC 2097154  // encoded one-hot [N, K]

typedef __attribute__((ext_vector_type(8))) short short8;   // 8 bf16 (4 VGPRs)
typedef __attribute__((ext_vector_type(4))) float f32x4;    // MFMA C/D

__device__ __forceinline__ unsigned short f2bf(float f) {   // RNE f32->bf16
    unsigned u = __builtin_bit_cast(unsigned, f);
    u += 0x7fffu + ((u >> 16) & 1u);
    return (unsigned short)(u >> 16);
}
__device__ __forceinline__ float bf2f(unsigned short h) {
    unsigned u = ((unsigned)h) << 16;
    return __builtin_bit_cast(float, u);
}

// ---------------------------------------------------------------------------
// prep: build packed bf16 hi/lo A-fragment stream + ee[k] + zero counts.
// Efrag layout: [kt(64)][j(4)][lane(64)] x 16B, so the main k-loop's 4
// fragment loads are each perfectly coalesced (64 lanes x 16B contiguous).
__global__ __launch_bounds__(64) void vq_prep(
    const float* __restrict__ E, unsigned short* __restrict__ Efrag,
    float* __restrict__ ee, int* __restrict__ counts)
{
    const int t = threadIdx.x;
    const int kt = blockIdx.x;
    const int code = kt * 16 + (t & 15);
    const int q = t >> 4;

    const float* ep0 = E + code * 64 + q * 8;        // d = q*8 .. q*8+7
    const float* ep1 = ep0 + 32;                     // d = 32+q*8 ..
    short8 ah0, ah1, al0, al1;
    float s = 0.f;
    #pragma unroll
    for (int j = 0; j < 8; ++j) {
        float v0 = ep0[j];
        unsigned short h0 = f2bf(v0);
        ah0[j] = (short)h0;
        al0[j] = (short)f2bf(v0 - bf2f(h0));
        s = fmaf(v0, v0, s);
        float v1 = ep1[j];
        unsigned short h1 = f2bf(v1);
        ah1[j] = (short)h1;
        al1[j] = (short)f2bf(v1 - bf2f(h1));
        s = fmaf(v1, v1, s);
    }
    short8* dst = (short8*)Efrag + (size_t)kt * 256;  // 4 frag-planes x 64 lanes
    dst[0 * 64 + t] = ah0;
    dst[1 * 64 + t] = ah1;
    dst[2 * 64 + t] = al0;
    dst[3 * 64 + t] = al1;

    // ||e||^2: reduce partial s across the 4 quads sharing this code
    s += __shfl_xor(s, 16);
    s += __shfl_xor(s, 32);
    if (t < 16) ee[code] = s;

    // zero counts (4096 threads total, need 1024)
    const int gid = blockIdx.x * 64 + t;
    if (gid < 1024) counts[gid] = 0;
}

// ---------------------------------------------------------------------------
// main: 512 blocks x 256 threads. Block owns 64 consecutive n; wave w owns
// codes [w*256,(w+1)*256) = tiles w*16..w*16+15, processing 4 n-tiles per
// k-tile (24 MFMA per 4 coalesced fragment loads — R10 showed the fragment
// load path is first-order, so maximize MFMA:load and halve Efrag traffic
// vs the R9 32-n blocks). R9 lesson: regular write-back stores (NT is ~40%
// slower for full-line streams). R7 lesson: no device-scope fence /
// last-block finalize fused here.
__global__ __launch_bounds__(256, 2) void vq_main(
    const float* __restrict__ X, const float* __restrict__ E,
    const unsigned short* __restrict__ Efrag, const float* __restrict__ ee,
    float* __restrict__ out, int* __restrict__ counts,
    float* __restrict__ lossPart)
{
    __shared__ float s_ee[1024];
    __shared__ float s_val[4][64];
    __shared__ int   s_idx[4][64];
    __shared__ float s_loss[4];

    const int t = threadIdx.x;
    const int l = t & 63;
    const int w = __builtin_amdgcn_readfirstlane(t >> 6);
    const int col = l & 15;
    const int quad = l >> 4;
    const int n0 = blockIdx.x * 64;
    const int b = n0 >> 10;          // 64 | 1024 -> uniform per block
    const int hwb = n0 & 1023;

    ((float4*)s_ee)[t] = ((const float4*)ee)[t];

    // B-fragments (x): B[d][n]: n = col + 16*nt, d = ks*32 + quad*8 + j
    short8 bh[4][2], bl[4][2];
    const float* xb = X + (size_t)b * 65536 + hwb;
    #pragma unroll
    for (int nt = 0; nt < 4; ++nt) {
        const float* xn = xb + nt * 16 + col;
        #pragma unroll
        for (int ks = 0; ks < 2; ++ks) {
            short8 vh, vl;
            #pragma unroll
            for (int j = 0; j < 8; ++j) {
                float v = xn[(size_t)(ks * 32 + quad * 8 + j) * 1024];
                unsigned short hb = f2bf(v);
                vh[j] = (short)hb;
                vl[j] = (short)f2bf(v - bf2f(hb));
            }
            bh[nt][ks] = vh;
            bl[nt][ks] = vl;
        }
    }

    __syncthreads();

    // --- k-loop over this wave's 16 tiles; all fragment loads coalesced ---
    float best[4] = {3.4e38f, 3.4e38f, 3.4e38f, 3.4e38f};
    int   bidx[4] = {0, 0, 0, 0};
    const short8* fw = (const short8*)Efrag + (size_t)(w * 16) * 256;
    #pragma unroll 2
    for (int kt = 0; kt < 16; ++kt) {
        const int kb = w * 256 + kt * 16;
        const short8* fb = fw + (size_t)kt * 256;
        short8 ah0 = fb[0 * 64 + l];     // 64 lanes x 16B contiguous
        short8 ah1 = fb[1 * 64 + l];
        short8 al0 = fb[2 * 64 + l];
        short8 al1 = fb[3 * 64 + l];
        f32x4 eev = *((const f32x4*)&s_ee[kb + quad * 4]);
        #pragma unroll
        for (int nt = 0; nt < 4; ++nt) {
            f32x4 c = {0.f, 0.f, 0.f, 0.f};
            c = __builtin_amdgcn_mfma_f32_16x16x32_bf16(ah0, bh[nt][0], c, 0, 0, 0);
            c = __builtin_amdgcn_mfma_f32_16x16x32_bf16(ah1, bh[nt][1], c, 0, 0, 0);
            c = __builtin_amdgcn_mfma_f32_16x16x32_bf16(al0, bh[nt][0], c, 0, 0, 0);
            c = __builtin_amdgcn_mfma_f32_16x16x32_bf16(al1, bh[nt][1], c, 0, 0, 0);
            c = __builtin_amdgcn_mfma_f32_16x16x32_bf16(ah0, bl[nt][0], c, 0, 0, 0);
            c = __builtin_amdgcn_mfma_f32_16x16x32_bf16(ah1, bl[nt][1], c, 0, 0, 0);
            // C/D: col = lane&15 (n), row = quad*4 + r (k within tile)
            #pragma unroll
            for (int r = 0; r < 4; ++r) {
                float val = fmaf(-2.f, c[r], eev[r]);
                int k = kb + quad * 4 + r;
                if (val < best[nt]) { best[nt] = val; bidx[nt] = k; }
            }
        }
    }

    // reduce across quads (lanes l, l^16, l^32, l^48 share (nt,col))
    #pragma unroll
    for (int nt = 0; nt < 4; ++nt) {
        float v = best[nt]; int i = bidx[nt];
        float ov = __shfl_xor(v, 16); int oi = __shfl_xor(i, 16);
        if (ov < v || (ov == v && oi < i)) { v = ov; i = oi; }
        ov = __shfl_xor(v, 32); oi = __shfl_xor(i, 32);
        if (ov < v || (ov == v && oi < i)) { v = ov; i = oi; }
        best[nt] = v; bidx[nt] = i;
    }
    // quad q publishes n-tile nt=q: n_local = q*16 + col
    s_val[w][quad * 16 + col] = best[quad];
    s_idx[w][quad * 16 + col] = bidx[quad];
    __syncthreads();

    // cross-wave reduce (wave 0, 64 lanes = 64 n), publish idx + counts
    if (w == 0) {
        float fv = s_val[0][l]; int fi0 = s_idx[0][l];
        #pragma unroll
        for (int j = 1; j < 4; ++j) {
            float v = s_val[j][l]; int i = s_idx[j][l];
            if (v < fv || (v == fv && i < fi0)) { fv = v; fi0 = i; }
        }
        s_idx[0][l] = fi0;
        atomicAdd(&counts[fi0], 1);
    }
    __syncthreads();

    // quantized store + loss: lane l <-> n0+l, wave w handles d in [16w,16w+16)
    {
        const int fi = s_idx[0][l];
        const int hw = hwb + l;
        const int d0 = w << 4;
        const float* er = E + ((size_t)fi << 6) + d0;
        float4 g0 = *(const float4*)(er);
        float4 g1 = *(const float4*)(er + 4);
        float4 g2 = *(const float4*)(er + 8);
        float4 g3 = *(const float4*)(er + 12);
        float q[16] = {g0.x, g0.y, g0.z, g0.w, g1.x, g1.y, g1.z, g1.w,
                       g2.x, g2.y, g2.z, g2.w, g3.x, g3.y, g3.z, g3.w};
        float* op = out + OUT_OFF_Q + (size_t)b * 65536 + hw;
        const float* xp = X + (size_t)b * 65536 + hw;
        float lsum = 0.f;
        #pragma unroll
        for (int dd = 0; dd < 16; ++dd) {
            const int d = d0 + dd;
            op[(size_t)d * 1024] = q[dd];           // coalesced (64-wide, 256B)
            float diff = q[dd] - xp[(size_t)d * 1024];
            lsum = fmaf(diff, diff, lsum);
        }
        #pragma unroll
        for (int off = 32; off; off >>= 1) lsum += __shfl_down(lsum, off);
        if (l == 0) s_loss[w] = lsum;
    }
    __syncthreads();
    if (t == 0)
        lossPart[blockIdx.x] = s_loss[0] + s_loss[1] + s_loss[2] + s_loss[3];

    // fused one-hot encode: wave w writes rows [16w, 16w+16), regular f32x4
    // stores (1 KB contiguous per wave-instruction = 16 full 64B lines)
    {
        f32x4* enc = (f32x4*)(out + OUT_OFF_ENC);
        const int rbase = w << 4;
        #pragma unroll 4
        for (int rr = 0; rr < 16; ++rr) {
            const int r = rbase + rr;
            const int ridx = s_idx[0][r];
            f32x4* erow = enc + (size_t)(n0 + r) * 256;
            #pragma unroll
            for (int c4 = 0; c4 < 4; ++c4) {
                const int kb4 = (c4 << 8) + (l << 2);
                f32x4 v = {0.f, 0.f, 0.f, 0.f};
                const int dlt = ridx - kb4;
                if (dlt == 0) v.x = 1.f;
                else if (dlt == 1) v.y = 1.f;
                else if (dlt == 2) v.z = 1.f;
                else if (dlt == 3) v.w = 1.f;
                erow[(c4 << 6) + l] = v;            // regular store
            }
        }
    }
}

// ---------------------------------------------------------------------------
__global__ __launch_bounds__(1024) void vq_finalize(
    const int* __restrict__ counts, const float* __restrict__ lossPart,
    float* __restrict__ out)
{
    __shared__ float redp[16];
    __shared__ float redl[16];
    const int t = threadIdx.x;
    const float p = (float)counts[t] * (1.0f / 32768.0f);
    float v = p * logf(p + 1e-10f);
    float ls = (t < 512) ? lossPart[t] : 0.f;
    #pragma unroll
    for (int off = 32; off; off >>= 1) {
        v += __shfl_down(v, off);
        ls += __shfl_down(ls, off);
    }
    if ((t & 63) == 0) { redp[t >> 6] = v; redl[t >> 6] = ls; }
    __syncthreads();
    if (t == 0) {
        float s = 0.f, sl = 0.f;
        #pragma unroll
        for (int i = 0; i < 16; ++i) { s += redp[i]; sl += redl[i]; }
        out[OUT_OFF_PPL] = expf(-s);
        out[OUT_OFF_VQ] = 1.25f * sl * (1.0f / 2097152.0f);
    }
}

extern "C" void kernel_launch(void* const* d_in, const int* in_sizes, int n_in,
                              void* d_out, int out_size, void* d_ws, size_t ws_size,
                              hipStream_t stream) {
    const float* X = (const float*)d_in[0];   // [32, 64, 32, 32] fp32
    const float* E = (const float*)d_in[1];   // [1024, 64] fp32
    float* out = (float*)d_out;

    // ws layout
    int* counts = (int*)d_ws;                                      // 4 KiB
    float* lossPart = (float*)((char*)d_ws + 4096);                // 2 KiB (512)
    float* ee = (float*)((char*)d_ws + 8192);                      // 4 KiB
    unsigned short* Efrag = (unsigned short*)((char*)d_ws + 12288);// 256 KiB

    vq_prep<<<64, 64, 0, stream>>>(E, Efrag, ee, counts);
    vq_main<<<512, 256, 0, stream>>>(X, E, Efrag, ee, out, counts, lossPart);
    vq_finalize<<<1, 1024, 0, stream>>>(counts, lossPart, out);
}

// Round 12
// 168.470 us; speedup vs baseline: 1.1043x; 1.0259x over previous
//
#include <hip/hip_runtime.h>

// Problem constants: B=32, D=64, H=W=32 -> N=32768 rows; K=1024 codes
#define OUT_OFF_Q 0          // quantized (straight-through fwd) [B,D,H,W]
#define OUT_OFF_VQ 2097152   // scalar vq_loss
#define OUT_OFF_PPL 2097153  // scalar perplexity
#define OUT_OFF_ENC 2097154  // encoded one-hot [N, K]

typedef __attribute__((ext_vector_type(8))) short short8;   // 8 bf16 (4 VGPRs)
typedef __attribute__((ext_vector_type(4))) float f32x4;    // MFMA C/D

__device__ __forceinline__ unsigned short f2bf(float f) {   // RNE f32->bf16
    unsigned u = __builtin_bit_cast(unsigned, f);
    u += 0x7fffu + ((u >> 16) & 1u);
    return (unsigned short)(u >> 16);
}
__device__ __forceinline__ float bf2f(unsigned short h) {
    unsigned u = ((unsigned)h) << 16;
    return __builtin_bit_cast(float, u);
}

// ---------------------------------------------------------------------------
// prep: build packed bf16 hi/lo A-fragment stream + ee[k] + zero counts.
// Efrag layout: [kt(64)][j(4)][lane(64)] x 16B, so the main k-loop's 4
// fragment loads are each perfectly coalesced (64 lanes x 16B contiguous).
__global__ __launch_bounds__(64) void vq_prep(
    const float* __restrict__ E, unsigned short* __restrict__ Efrag,
    float* __restrict__ ee, int* __restrict__ counts)
{
    const int t = threadIdx.x;
    const int kt = blockIdx.x;
    const int code = kt * 16 + (t & 15);
    const int q = t >> 4;

    const float* ep0 = E + code * 64 + q * 8;        // d = q*8 .. q*8+7
    const float* ep1 = ep0 + 32;                     // d = 32+q*8 ..
    short8 ah0, ah1, al0, al1;
    float s = 0.f;
    #pragma unroll
    for (int j = 0; j < 8; ++j) {
        float v0 = ep0[j];
        unsigned short h0 = f2bf(v0);
        ah0[j] = (short)h0;
        al0[j] = (short)f2bf(v0 - bf2f(h0));
        s = fmaf(v0, v0, s);
        float v1 = ep1[j];
        unsigned short h1 = f2bf(v1);
        ah1[j] = (short)h1;
        al1[j] = (short)f2bf(v1 - bf2f(h1));
        s = fmaf(v1, v1, s);
    }
    short8* dst = (short8*)Efrag + (size_t)kt * 256;  // 4 frag-planes x 64 lanes
    dst[0 * 64 + t] = ah0;
    dst[1 * 64 + t] = ah1;
    dst[2 * 64 + t] = al0;
    dst[3 * 64 + t] = al1;

    // ||e||^2: reduce partial s across the 4 quads sharing this code
    s += __shfl_xor(s, 16);
    s += __shfl_xor(s, 32);
    if (t < 16) ee[code] = s;

    // zero counts (4096 threads total, need 1024)
    const int gid = blockIdx.x * 64 + t;
    if (gid < 1024) counts[gid] = 0;
}

// ---------------------------------------------------------------------------
// main (R9 geometry + latency fixes): 1024 blocks x 256 threads. Block owns
// 32 consecutive n; wave w owns codes [w*256,(w+1)*256) = tiles w*16..+15.
// R12: (a) explicit register double-buffer of the next k-tile's fragments
// (branch-free (kt+1)&15 wrap) so L2 latency is covered by the 12 MFMAs of
// the current tile; (b) eev read straight from global ee (L1-hot, 1KB/wave)
// -> drops the s_ee LDS stage and its __syncthreads.
// R9 lesson: regular write-back stores (NT ~40% slower for full-line
// streams). R7 lesson: no device-scope fence / fused finalize.
__global__ __launch_bounds__(256, 4) void vq_main(
    const float* __restrict__ X, const float* __restrict__ E,
    const unsigned short* __restrict__ Efrag, const float* __restrict__ ee,
    float* __restrict__ out, int* __restrict__ counts,
    float* __restrict__ lossPart)
{
    __shared__ float s_val[4][32];
    __shared__ int   s_idx[4][32];
    __shared__ float s_loss[4];

    const int t = threadIdx.x;
    const int l = t & 63;
    const int w = __builtin_amdgcn_readfirstlane(t >> 6);
    const int col = l & 15;
    const int quad = l >> 4;
    const int n0 = blockIdx.x * 32;
    const int b = n0 >> 10;
    const int hwb = n0 & 1023;

    // B-fragments (x): B[d][n]: n = col + 16*nt, d = ks*32 + quad*8 + j
    short8 bh[2][2], bl[2][2];
    const float* xb = X + (size_t)b * 65536 + hwb;
    #pragma unroll
    for (int nt = 0; nt < 2; ++nt) {
        const float* xn = xb + nt * 16 + col;
        #pragma unroll
        for (int ks = 0; ks < 2; ++ks) {
            short8 vh, vl;
            #pragma unroll
            for (int j = 0; j < 8; ++j) {
                float v = xn[(size_t)(ks * 32 + quad * 8 + j) * 1024];
                unsigned short hb = f2bf(v);
                vh[j] = (short)hb;
                vl[j] = (short)f2bf(v - bf2f(hb));
            }
            bh[nt][ks] = vh;
            bl[nt][ks] = vl;
        }
    }

    // --- k-loop over this wave's 16 tiles; register double-buffer ---
    float best[2] = {3.4e38f, 3.4e38f};
    int   bidx[2] = {0, 0};
    const short8* fw = (const short8*)Efrag + (size_t)(w * 16) * 256;
    short8 ah0 = fw[0 * 64 + l];     // tile 0 fragments
    short8 ah1 = fw[1 * 64 + l];
    short8 al0 = fw[2 * 64 + l];
    short8 al1 = fw[3 * 64 + l];
    for (int kt = 0; kt < 16; ++kt) {
        // prefetch next tile (wraps to 0 on last iter — branch-free, harmless)
        const short8* fb = fw + (size_t)((kt + 1) & 15) * 256;
        short8 ph0 = fb[0 * 64 + l];
        short8 ph1 = fb[1 * 64 + l];
        short8 pl0 = fb[2 * 64 + l];
        short8 pl1 = fb[3 * 64 + l];

        const int kb = w * 256 + kt * 16;
        f32x4 eev = *((const f32x4*)(ee + kb + quad * 4));   // L1-hot
        #pragma unroll
        for (int nt = 0; nt < 2; ++nt) {
            f32x4 c = {0.f, 0.f, 0.f, 0.f};
            c = __builtin_amdgcn_mfma_f32_16x16x32_bf16(ah0, bh[nt][0], c, 0, 0, 0);
            c = __builtin_amdgcn_mfma_f32_16x16x32_bf16(ah1, bh[nt][1], c, 0, 0, 0);
            c = __builtin_amdgcn_mfma_f32_16x16x32_bf16(al0, bh[nt][0], c, 0, 0, 0);
            c = __builtin_amdgcn_mfma_f32_16x16x32_bf16(al1, bh[nt][1], c, 0, 0, 0);
            c = __builtin_amdgcn_mfma_f32_16x16x32_bf16(ah0, bl[nt][0], c, 0, 0, 0);
            c = __builtin_amdgcn_mfma_f32_16x16x32_bf16(ah1, bl[nt][1], c, 0, 0, 0);
            // C/D: col = lane&15 (n), row = quad*4 + r (k within tile)
            #pragma unroll
            for (int r = 0; r < 4; ++r) {
                float val = fmaf(-2.f, c[r], eev[r]);
                int k = kb + quad * 4 + r;
                if (val < best[nt]) { best[nt] = val; bidx[nt] = k; }
            }
        }
        ah0 = ph0; ah1 = ph1; al0 = pl0; al1 = pl1;
    }

    // reduce across quads (lanes l, l^16, l^32, l^48 share (nt,col))
    #pragma unroll
    for (int nt = 0; nt < 2; ++nt) {
        float v = best[nt]; int i = bidx[nt];
        float ov = __shfl_xor(v, 16); int oi = __shfl_xor(i, 16);
        if (ov < v || (ov == v && oi < i)) { v = ov; i = oi; }
        ov = __shfl_xor(v, 32); oi = __shfl_xor(i, 32);
        if (ov < v || (ov == v && oi < i)) { v = ov; i = oi; }
        best[nt] = v; bidx[nt] = i;
    }
    if (quad < 2) {
        s_val[w][quad * 16 + col] = best[quad];
        s_idx[w][quad * 16 + col] = bidx[quad];
    }
    __syncthreads();

    // cross-wave reduce, publish idx + counts
    if (t < 32) {
        float fv = s_val[0][t]; int fi0 = s_idx[0][t];
        #pragma unroll
        for (int j = 1; j < 4; ++j) {
            float v = s_val[j][t]; int i = s_idx[j][t];
            if (v < fv || (v == fv && i < fi0)) { fv = v; fi0 = i; }
        }
        s_idx[0][t] = fi0;
        atomicAdd(&counts[fi0], 1);
    }
    __syncthreads();

    // quantized store + loss: wave w handles d in [16w,16w+16) for 32 n.
    {
        const int nl = l & 31;
        const int half = l >> 5;
        const int fi = s_idx[0][nl];
        const int hw = hwb + nl;
        const int d0 = (w << 4) + (half << 3);
        const float* er = E + ((size_t)fi << 6) + d0;
        float4 g0 = *(const float4*)(er);
        float4 g1 = *(const float4*)(er + 4);
        float q[8] = {g0.x, g0.y, g0.z, g0.w, g1.x, g1.y, g1.z, g1.w};
        float* op = out + OUT_OFF_Q + (size_t)b * 65536 + hw;
        const float* xp = X + (size_t)b * 65536 + hw;
        float lsum = 0.f;
        #pragma unroll
        for (int dd = 0; dd < 8; ++dd) {
            const int d = d0 + dd;
            op[(size_t)d * 1024] = q[dd];           // regular coalesced store
            float diff = q[dd] - xp[(size_t)d * 1024];
            lsum = fmaf(diff, diff, lsum);
        }
        #pragma unroll
        for (int off = 32; off; off >>= 1) lsum += __shfl_down(lsum, off);
        if (l == 0) s_loss[w] = lsum;
    }
    __syncthreads();
    if (t == 0)
        lossPart[blockIdx.x] = s_loss[0] + s_loss[1] + s_loss[2] + s_loss[3];

    // fused one-hot encode: wave w writes rows [8w, 8w+8), regular f32x4
    // stores (1 KB contiguous per wave-instruction = 16 full 64B lines)
    {
        f32x4* enc = (f32x4*)(out + OUT_OFF_ENC);
        const int rbase = w << 3;
        for (int rr = 0; rr < 8; ++rr) {
            const int r = rbase + rr;
            const int ridx = s_idx[0][r];
            f32x4* erow = enc + (size_t)(n0 + r) * 256;
            #pragma unroll
            for (int c4 = 0; c4 < 4; ++c4) {
                const int kb4 = (c4 << 8) + (l << 2);
                f32x4 v = {0.f, 0.f, 0.f, 0.f};
                const int dlt = ridx - kb4;
                if (dlt == 0) v.x = 1.f;
                else if (dlt == 1) v.y = 1.f;
                else if (dlt == 2) v.z = 1.f;
                else if (dlt == 3) v.w = 1.f;
                erow[(c4 << 6) + l] = v;            // regular store
            }
        }
    }
}

// ---------------------------------------------------------------------------
__global__ __launch_bounds__(1024) void vq_finalize(
    const int* __restrict__ counts, const float* __restrict__ lossPart,
    float* __restrict__ out)
{
    __shared__ float redp[16];
    __shared__ float redl[16];
    const int t = threadIdx.x;
    const float p = (float)counts[t] * (1.0f / 32768.0f);
    float v = p * logf(p + 1e-10f);
    float ls = lossPart[t];
    #pragma unroll
    for (int off = 32; off; off >>= 1) {
        v += __shfl_down(v, off);
        ls += __shfl_down(ls, off);
    }
    if ((t & 63) == 0) { redp[t >> 6] = v; redl[t >> 6] = ls; }
    __syncthreads();
    if (t == 0) {
        float s = 0.f, sl = 0.f;
        #pragma unroll
        for (int i = 0; i < 16; ++i) { s += redp[i]; sl += redl[i]; }
        out[OUT_OFF_PPL] = expf(-s);
        out[OUT_OFF_VQ] = 1.25f * sl * (1.0f / 2097152.0f);
    }
}

extern "C" void kernel_launch(void* const* d_in, const int* in_sizes, int n_in,
                              void* d_out, int out_size, void* d_ws, size_t ws_size,
                              hipStream_t stream) {
    const float* X = (const float*)d_in[0];   // [32, 64, 32, 32] fp32
    const float* E = (const float*)d_in[1];   // [1024, 64] fp32
    float* out = (float*)d_out;

    // ws layout
    int* counts = (int*)d_ws;                                      // 4 KiB
    float* lossPart = (float*)((char*)d_ws + 4096);                // 4 KiB
    float* ee = (float*)((char*)d_ws + 8192);                      // 4 KiB
    unsigned short* Efrag = (unsigned short*)((char*)d_ws + 12288);// 256 KiB

    vq_prep<<<64, 64, 0, stream>>>(E, Efrag, ee, counts);
    vq_main<<<1024, 256, 0, stream>>>(X, E, Efrag, ee, out, counts, lossPart);
    vq_finalize<<<1, 1024, 0, stream>>>(counts, lossPart, out);
}